// Round 1
// 253.141 us; speedup vs baseline: 1.0063x; 1.0063x over previous
//
#include <hip/hip_runtime.h>
#include <math.h>

// TGV-2 PDHG, B=2, H=W=256, T=128.
// R14 = R9 + trapezoid active-set gating. The region shrinks 1 ring/iter in
// validity; R9 computed all 32x48 px all 8 iters anyway. Row-wise active
// sets (wave-granular: each wave spans ~2.67 full rows, so row gating is
// what s_cbranch_execz can actually skip):
//   publish ub/vb : rows [t, 31-t]
//   dual (p,q)    : rows [t, 30-t]   (also publishes p,q)
//   primal (u,v)  : rows [t+1, 30-t]
// ~18% of wave-iterations skip the whole body; interior waves gain issue
// slots on their SIMD (body is issue-bound: 6->12 waves was only +6%).
// Valid px run bit-identical math -> absmax unchanged.
// Everything else = R9 (best measured 254.7us): 16 launches x 8 trapezoid
// iters, region 32x48 (tile 16x32, halo 8), 256 blocks (1/CU), 768 threads
// (12 waves), 1x2 strips, packed v_pk_f32 math, 0/1 mask multipliers,
// rsq+min projection, vb1/vb2 interleaved LDS pair, init folded into
// launch 0, final launch stores only u.

namespace {

typedef float v2f __attribute__((ext_vector_type(2)));

constexpr int kN = 2 * 256 * 256;
constexpr float kTau = 0.28867513459481287f;  // 1/sqrt(12) (f32)
constexpr float kSigma = kTau;
constexpr float kInv1pTau = 1.0f / (1.0f + kTau);

constexpr int RR = 32;          // region rows (H)
constexpr int RC = 48;          // region cols (W)
constexpr int A = RR * RC;      // 1536 floats per LDS array
constexpr int PAD = 64;         // rim-overread safety pads (front/back)
constexpr int TILE_R = 16;
constexpr int TILE_C = 32;
constexpr int HALO = 8;         // = iterations per launch
constexpr int NLAUNCH = 128 / HALO;      // 16
constexpr int NTHREADS = RR * (RC / 2);  // 768 = 12 waves

__device__ __forceinline__ float4 ld4(const float* p) {
  return *reinterpret_cast<const float4*>(p);
}

// ws layout: 10 arrays of kN floats: ub, v1, v2, vb1, vb2, p1, p2, q11, q22, q12
__global__ __launch_bounds__(NTHREADS, 3) void tgv8_kernel(
    const float* __restrict__ f, const float* __restrict__ rp,
    float* __restrict__ ug, float* __restrict__ ws, int t0) {
  float* ubg = ws + 0 * kN;
  float* v1g = ws + 1 * kN;
  float* v2g = ws + 2 * kN;
  float* vb1g = ws + 3 * kN;
  float* vb2g = ws + 4 * kN;
  float* p1g = ws + 5 * kN;
  float* p2g = ws + 6 * kN;
  float* q11g = ws + 7 * kN;
  float* q22g = ws + 8 * kN;
  float* q12g = ws + 9 * kN;

  // LDS: ub (A) + vb-pair (2A) + p1,p2,q11,q22,q12 (5A) = 8A floats
  __shared__ __align__(16) float smem[PAD + 8 * A + PAD];
  float* ubS = smem + PAD;
  float* vbS = ubS + A;       // interleaved [vb1, vb2] per pixel, 2A floats
  float* p1S = vbS + 2 * A;
  float* p2S = p1S + A;
  float* q11S = p2S + A;
  float* q22S = q11S + A;
  float* q12S = q22S + A;

  const int tid = threadIdx.x;
  const int r = tid / 24;        // region row 0..31
  const int c = (tid % 24) * 2;  // region col (float2-aligned)
  const int rc = r * RC + c;

  const int gi = blockIdx.y * TILE_R + r - HALO;  // global row (may be OOB)
  const int gj = blockIdx.x * TILE_C + c - HALO;  // global col (even)
  const bool inImg = ((unsigned)gi < 256u) && ((unsigned)gj < 256u);
  const int base = blockIdx.z * 65536 + gi * 256 + gj;

  const float alpha0 = rp[0];
  const float alpha1 = rp[1];

  // ---- boundary masks as 0/1 multipliers (thread-constant) ----
  const float mD = (gi != 255) ? 1.f : 0.f;  // has down neighbor (H fwd)
  const float mU = (gi != 0) ? 1.f : 0.f;    // has up neighbor (H bwd)
  v2f mR, mL;
  mR.x = (gj + 0 != 255) ? 1.f : 0.f;
  mR.y = (gj + 1 != 255) ? 1.f : 0.f;
  mL.x = (gj != 0) ? 1.f : 0.f;
  mL.y = 1.f;

  // state: one packed v2f per field
  v2f u_, ub_, v1_, v2_, vb1_, vb2_, p1_, p2_, q11_, q22_, q12_, f_;

#define LOADV(dst, src) dst = *reinterpret_cast<const v2f*>((src) + base);
  if (inImg) {
    LOADV(f_, f)
    if (t0 == 0) {
      // PDHG initial state: u = ub = f, everything else zero.
      u_ = f_; ub_ = f_;
      v1_ = 0.f; v2_ = 0.f; vb1_ = 0.f; vb2_ = 0.f;
      p1_ = 0.f; p2_ = 0.f; q11_ = 0.f; q22_ = 0.f; q12_ = 0.f;
    } else {
      LOADV(u_, ug)
      LOADV(ub_, ubg)
      LOADV(v1_, v1g)
      LOADV(v2_, v2g)
      LOADV(vb1_, vb1g)
      LOADV(vb2_, vb2g)
      LOADV(p1_, p1g)
      LOADV(p2_, p2g)
      LOADV(q11_, q11g)
      LOADV(q22_, q22g)
      LOADV(q12_, q12g)
    }
  } else {
    f_ = 0.f; u_ = 0.f; ub_ = 0.f;
    v1_ = 0.f; v2_ = 0.f; vb1_ = 0.f; vb2_ = 0.f;
    p1_ = 0.f; p2_ = 0.f; q11_ = 0.f; q22_ = 0.f; q12_ = 0.f;
  }
#undef LOADV

  for (int t = 0; t < HALO; ++t) {
    // Active-set gating (row-wise, wave-granular). Validity shrinks one ring
    // per iteration; rows outside the sets below produce values that are
    // never read by any valid pixel (LDS always holds finite stale data, so
    // skipped publishes are harmless).
    const bool pubD = (r >= t) && (r <= 31 - t);
    const bool actD = (r >= t) && (r <= 30 - t);
    const bool actP = (r >= t + 1) && (r <= 30 - t);

    // ---- publish dual halos: ub (b64), vb pair (b128) ----
    if (pubD) {
      *reinterpret_cast<v2f*>(ubS + rc) = ub_;
      float4 vp;
      vp.x = vb1_.x; vp.y = vb2_.x; vp.z = vb1_.y; vp.w = vb2_.y;
      *reinterpret_cast<float4*>(vbS + 2 * rc) = vp;
    }
    __syncthreads();

    if (actD) {
      // ---- dual ascent + projections ----
      const float ubX = ubS[rc + 2];  // right-edge scalar neighbor
      const v2f vbX = *reinterpret_cast<const v2f*>(vbS + 2 * (rc + 2));
      const v2f ubD = *reinterpret_cast<const v2f*>(ubS + rc + RC);
      const float4 vd = ld4(vbS + 2 * (rc + RC));
      v2f vb1D, vb2D;
      vb1D.x = vd.x; vb1D.y = vd.z;
      vb2D.x = vd.y; vb2D.y = vd.w;

      v2f ubr, vb1r, vb2r;  // right-shifted (element e+1)
      ubr.x = ub_.y;   ubr.y = ubX;
      vb1r.x = vb1_.y; vb1r.y = vbX.x;
      vb2r.x = vb2_.y; vb2r.y = vbX.y;

      // p update
      const v2f du1 = mD * (ubD - ub_);
      const v2f du2 = mR * (ubr - ub_);
      const v2f pn1 = p1_ + kSigma * (du1 - vb1_);
      const v2f pn2 = p2_ + kSigma * (du2 - vb2_);
      const v2f n2p = pn1 * pn1 + pn2 * pn2;
      v2f sp;
      sp.x = fminf(1.f, alpha1 * __builtin_amdgcn_rsqf(n2p.x));
      sp.y = fminf(1.f, alpha1 * __builtin_amdgcn_rsqf(n2p.y));
      p1_ = pn1 * sp;
      p2_ = pn2 * sp;

      // q update (e11, e22, e12)
      const v2f e11 = mD * (vb1D - vb1_);
      const v2f e22 = mR * (vb2r - vb2_);
      const v2f e12 = 0.5f * (mR * (vb1r - vb1_) + mD * (vb2D - vb2_));
      const v2f qn1 = q11_ + kSigma * e11;
      const v2f qn2 = q22_ + kSigma * e22;
      const v2f qn3 = q12_ + kSigma * e12;
      const v2f n2q = qn1 * qn1 + qn2 * qn2 + 2.f * (qn3 * qn3);
      v2f sq;
      sq.x = fminf(1.f, alpha0 * __builtin_amdgcn_rsqf(n2q.x));
      sq.y = fminf(1.f, alpha0 * __builtin_amdgcn_rsqf(n2q.y));
      q11_ = qn1 * sq;
      q22_ = qn2 * sq;
      q12_ = qn3 * sq;

      // ---- publish primal halos (new p, q) ----
      *reinterpret_cast<v2f*>(p1S + rc) = p1_;
      *reinterpret_cast<v2f*>(p2S + rc) = p2_;
      *reinterpret_cast<v2f*>(q11S + rc) = q11_;
      *reinterpret_cast<v2f*>(q22S + rc) = q22_;
      *reinterpret_cast<v2f*>(q12S + rc) = q12_;
    }
    __syncthreads();

    if (actP) {
      // ---- primal descent + over-relaxation ----
      const v2f p1U = *reinterpret_cast<const v2f*>(p1S + rc - RC);
      const v2f q11U = *reinterpret_cast<const v2f*>(q11S + rc - RC);
      const v2f q12U = *reinterpret_cast<const v2f*>(q12S + rc - RC);
      const float p2Ls = p2S[rc - 1];   // left-edge scalar neighbors
      const float q22Ls = q22S[rc - 1];
      const float q12Ls = q12S[rc - 1];

      v2f p2l, q22l, q12l;  // left-shifted (element e-1)
      p2l.x = p2Ls;   p2l.y = p2_.x;
      q22l.x = q22Ls; q22l.y = q22_.x;
      q12l.x = q12Ls; q12l.y = q12_.x;

      const v2f divp = mD * p1_ + mR * p2_ - (mU * p1U + mL * p2l);
      const v2f un = (u_ + kTau * divp + kTau * f_) * kInv1pTau;
      ub_ = 2.f * un - u_;
      u_ = un;

      const v2f c1 = mD * q11_ + mR * q12_ - (mU * q11U + mL * q12l);
      const v2f c2 = mD * q12_ + mR * q22_ - (mU * q12U + mL * q22l);
      const v2f v1n = v1_ + kTau * (p1_ + c1);
      const v2f v2n = v2_ + kTau * (p2_ + c2);
      vb1_ = 2.f * v1n - v1_;
      v1_ = v1n;
      vb2_ = 2.f * v2n - v2_;
      v2_ = v2n;
    }
  }

  // ---- store interior 16x32 (exact after 8 iters) ----
  if (r >= HALO && r < HALO + TILE_R && c >= HALO && c < HALO + TILE_C) {
#define STOREV(src, dst) *reinterpret_cast<v2f*>((dst) + base) = src;
    STOREV(u_, ug)
    if (t0 != NLAUNCH - 1) {  // ws is dead after the final launch
      STOREV(ub_, ubg)
      STOREV(v1_, v1g)
      STOREV(v2_, v2g)
      STOREV(vb1_, vb1g)
      STOREV(vb2_, vb2g)
      STOREV(p1_, p1g)
      STOREV(p2_, p2g)
      STOREV(q11_, q11g)
      STOREV(q22_, q22g)
      STOREV(q12_, q12g)
    }
#undef STOREV
  }
}

}  // namespace

extern "C" void kernel_launch(void* const* d_in, const int* in_sizes, int n_in,
                              void* d_out, int out_size, void* d_ws,
                              size_t ws_size, hipStream_t stream) {
  const float* f = (const float*)d_in[0];
  const float* rp = (const float*)d_in[1];  // [alpha0, alpha1]
  // d_in[2] is T = 128 (fixed; trip count must be static for graph capture).

  float* u = (float*)d_out;
  float* ws = (float*)d_ws;

  dim3 grid(256 / TILE_C, 256 / TILE_R, 2);  // 8 x 16 x 2 = 256 blocks
  for (int t = 0; t < NLAUNCH; ++t) {        // 16 launches x 8 iterations
    hipLaunchKernelGGL(tgv8_kernel, grid, dim3(NTHREADS), 0, stream, f, rp, u,
                       ws, t);
  }
}